// Round 2
// baseline (936.339 us; speedup 1.0000x reference)
//
#include <hip/hip_runtime.h>
#include <hip/hip_bf16.h>

#define N_TOK 4096
#define DIM   1024
#define VOCAB 32000
#define BM 128
#define BN 128
#define BK 32
#define TBLK 5          // vocab tiles per block (epilogue amortization)
#define SMOOTH 0.1f

typedef __attribute__((ext_vector_type(8))) short short8v;
typedef __attribute__((ext_vector_type(4))) float float4v;

__device__ __forceinline__ unsigned short f2bf(float f) {
  union { float f; unsigned u; } c; c.f = f;
  unsigned r = c.u + 0x7fffu + ((c.u >> 16) & 1u);
  return (unsigned short)(r >> 16);
}

// f32 -> bf16 (RNE), 4 elems/thread, coalesced float4 in / 8B out
__global__ void cvt_bf16(const float* __restrict__ src, unsigned short* __restrict__ dst, int n4) {
  int i = blockIdx.x * blockDim.x + threadIdx.x;
  if (i >= n4) return;
  float4 v = ((const float4*)src)[i];
  unsigned long long p = (unsigned long long)f2bf(v.x)
                       | ((unsigned long long)f2bf(v.y) << 16)
                       | ((unsigned long long)f2bf(v.z) << 32)
                       | ((unsigned long long)f2bf(v.w) << 48);
  ((unsigned long long*)dst)[i] = p;
}

__device__ __forceinline__ void gload_lds16(const unsigned short* g, unsigned short* l) {
  __builtin_amdgcn_global_load_lds((const __attribute__((address_space(1))) unsigned int*)g,
                                   (__attribute__((address_space(3))) unsigned int*)l,
                                   16, 0, 0);
}

// logit[n, y_n] in exact f32: one wave per token row.
__global__ __launch_bounds__(256)
void tgt_dot(const float* __restrict__ x, const float* __restrict__ W,
             const int* __restrict__ y, float* __restrict__ tgtRow) {
  const int n = blockIdx.x * 4 + (threadIdx.x >> 6);
  const int lane = threadIdx.x & 63;
  const float4* xr = (const float4*)(x + (size_t)n * DIM);
  const float4* wr = (const float4*)(W + (size_t)y[n] * DIM);
  float d = 0.f;
#pragma unroll
  for (int i = 0; i < 4; ++i) {
    float4 a = xr[lane + 64 * i], b = wr[lane + 64 * i];
    d += a.x * b.x + a.y * b.y + a.z * b.z + a.w * b.w;
  }
#pragma unroll
  for (int off = 32; off > 0; off >>= 1) d += __shfl_xor(d, off, 64);
  if (lane == 0) tgtRow[n] = d;
}

// C = Xb[4096,1024] * Wb[32000,1024]^T with fused per-row sum(exp) / sum.
// 128x128 tile, 4 waves 2x2, 4x4 MFMAs 16x16x32 bf16; each block persists
// over TBLK consecutive vocab tiles, se/ss accumulate in registers.
// grid.x = token tile (fastest) => XCD = linear%8 = token%8: all vocab tiles
// of a token-slice stay on one XCD => W fetched past-L2 once per XCD.
__global__ __launch_bounds__(256)
void gemm_ce(const unsigned short* __restrict__ Xb, const unsigned short* __restrict__ Wb,
             float* __restrict__ rowExp, float* __restrict__ rowSum) {
  __shared__ __align__(16) unsigned short As[BM * BK];  // 8 KB
  __shared__ __align__(16) unsigned short Bs[BN * BK];  // 8 KB

  const int ib = blockIdx.x;   // token tile (32)
  const int vg = blockIdx.y;   // vocab group (50)
  const int row0 = ib * BM;

  const int tid  = threadIdx.x;
  const int wv   = tid >> 6;
  const int lane = tid & 63;
  const int wr = wv >> 1, wc = wv & 1;
  const int quad = lane >> 4;
  const int r16  = lane & 15;
  const int lrow = lane >> 2;        // 0..15: row within 16-row stage slab
  const int lcol = (lane & 3) * 8;   // k-offset (8 bf16 = 16B)
  (void)wc;

  float se[16], ss[16];
#pragma unroll
  for (int i = 0; i < 16; ++i) { se[i] = 0.f; ss[i] = 0.f; }

  for (int t = 0; t < TBLK; ++t) {
    const int col0 = (vg * TBLK + t) * BN;

    float4v acc[4][4];
#pragma unroll
    for (int i = 0; i < 4; ++i)
#pragma unroll
      for (int j = 0; j < 4; ++j) acc[i][j] = (float4v){0.f, 0.f, 0.f, 0.f};

    for (int kk = 0; kk < DIM; kk += BK) {
      __syncthreads();   // prior ds_reads done before overwrite
#pragma unroll
      for (int c = 0; c < 2; ++c) {
        const int rA = c * 64 + wv * 16;   // wave-uniform slab base
        gload_lds16(Xb + (size_t)(row0 + rA + lrow) * DIM + kk + lcol, &As[rA * BK]);
        gload_lds16(Wb + (size_t)(col0 + rA + lrow) * DIM + kk + lcol, &Bs[rA * BK]);
      }
      __syncthreads();   // staging visible

      short8v af[4], bf[4];
#pragma unroll
      for (int i = 0; i < 4; ++i)
        af[i] = *(const short8v*)&As[(wr * 64 + i * 16 + r16) * BK + quad * 8];
#pragma unroll
      for (int j = 0; j < 4; ++j)
        bf[j] = *(const short8v*)&Bs[(wc * 64 + j * 16 + r16) * BK + quad * 8];
#pragma unroll
      for (int i = 0; i < 4; ++i)
#pragma unroll
        for (int j = 0; j < 4; ++j)
          acc[i][j] = __builtin_amdgcn_mfma_f32_16x16x32_bf16(af[i], bf[j], acc[i][j], 0, 0, 0);
    }

    // per-tile exp pass (register-only): C/D layout col=r16, row=quad*4+reg
#pragma unroll
    for (int i = 0; i < 4; ++i)
#pragma unroll
      for (int r = 0; r < 4; ++r) {
        const int idx = i * 4 + r;
#pragma unroll
        for (int j = 0; j < 4; ++j) {
          const float v = acc[i][j][r];
          ss[idx] += v;
          se[idx] += __expf(v);
        }
      }
  }

  // once per block: reduce across the 16 lanes (same quad) sharing each row
#pragma unroll
  for (int i = 0; i < 4; ++i)
#pragma unroll
    for (int r = 0; r < 4; ++r) {
      const int idx = i * 4 + r;
      float e = se[idx], s = ss[idx];
#pragma unroll
      for (int off = 1; off < 16; off <<= 1) {
        e += __shfl_xor(e, off, 64);
        s += __shfl_xor(s, off, 64);
      }
      if (r16 == 0) {
        const int rloc = wr * 64 + i * 16 + quad * 4 + r;
        atomicAdd(&rowExp[row0 + rloc], e);
        atomicAdd(&rowSum[row0 + rloc], s);
      }
    }
}

// loss = (1/N) sum lse - (1-s)/N * sum tgt - s/(N*V) * sum(all logits)
__global__ void finalize_kernel(const float* __restrict__ rowExp, const float* __restrict__ rowSum,
                                const float* __restrict__ tgtRow, float* __restrict__ out) {
  __shared__ float s1[256], s2[256], s3[256];
  const int t = threadIdx.x;
  float a = 0.f, b = 0.f, c = 0.f;
  for (int n = t; n < N_TOK; n += 256) {
    a += logf(rowExp[n]);
    b += rowSum[n];
    c += tgtRow[n];
  }
  s1[t] = a; s2[t] = b; s3[t] = c;
  __syncthreads();
  for (int o = 128; o > 0; o >>= 1) {
    if (t < o) { s1[t] += s1[t + o]; s2[t] += s2[t + o]; s3[t] += s3[t + o]; }
    __syncthreads();
  }
  if (t == 0) {
    const float inviN = 1.0f / (float)N_TOK;
    out[0] = s1[0] * inviN
           - (1.0f - SMOOTH) * s3[0] * inviN
           - SMOOTH * s2[0] / ((float)N_TOK * (float)VOCAB);
  }
}

extern "C" void kernel_launch(void* const* d_in, const int* in_sizes, int n_in,
                              void* d_out, int out_size, void* d_ws, size_t ws_size,
                              hipStream_t stream) {
  const float* x = (const float*)d_in[0];
  const float* W = (const float*)d_in[1];
  const int*   y = (const int*)d_in[2];
  float* out = (float*)d_out;

  char* ws = (char*)d_ws;
  float* rowExp = (float*)(ws);              // 4096 f32
  float* rowSum = (float*)(ws + 16384);      // 4096 f32
  float* tgtRow = (float*)(ws + 32768);      // 4096 f32 (fully written, no memset)
  unsigned short* Xb = (unsigned short*)(ws + 65536);                            // 8.4 MB
  unsigned short* Wb = (unsigned short*)(ws + 65536 + (size_t)N_TOK * DIM * 2);  // 65.5 MB

  hipMemsetAsync(ws, 0, 32768, stream);  // zero rowExp/rowSum (ws poisoned 0xAA)

  tgt_dot<<<N_TOK / 4, 256, 0, stream>>>(x, W, y, tgtRow);
  cvt_bf16<<<(N_TOK * DIM / 4 + 255) / 256, 256, 0, stream>>>(x, Xb, N_TOK * DIM / 4);
  cvt_bf16<<<(VOCAB * DIM / 4 + 255) / 256, 256, 0, stream>>>(W, Wb, VOCAB * DIM / 4);

  dim3 grid(N_TOK / BM, VOCAB / (BN * TBLK));  // (32, 50): token-fastest for XCD locality
  gemm_ce<<<grid, 256, 0, stream>>>(Xb, Wb, rowExp, rowSum);

  finalize_kernel<<<1, 256, 0, stream>>>(rowExp, rowSum, tgtRow, out);
}

// Round 3
// 578.013 us; speedup vs baseline: 1.6199x; 1.6199x over previous
//
#include <hip/hip_runtime.h>
#include <hip/hip_bf16.h>

#define N_TOK 4096
#define DIM   1024
#define VOCAB 32000
#define BM 128
#define BN 128
#define BK 64           // 64-deep K stage: 32 MFMAs per barrier drain, 16 iters
#define SMOOTH 0.1f

typedef __attribute__((ext_vector_type(8))) short short8v;
typedef __attribute__((ext_vector_type(4))) float float4v;

__device__ __forceinline__ unsigned short f2bf(float f) {
  union { float f; unsigned u; } c; c.f = f;
  unsigned r = c.u + 0x7fffu + ((c.u >> 16) & 1u);
  return (unsigned short)(r >> 16);
}

// f32 -> bf16 (RNE), 4 elems/thread, coalesced float4 in / 8B out
__global__ void cvt_bf16(const float* __restrict__ src, unsigned short* __restrict__ dst, int n4) {
  int i = blockIdx.x * blockDim.x + threadIdx.x;
  if (i >= n4) return;
  float4 v = ((const float4*)src)[i];
  unsigned long long p = (unsigned long long)f2bf(v.x)
                       | ((unsigned long long)f2bf(v.y) << 16)
                       | ((unsigned long long)f2bf(v.z) << 32)
                       | ((unsigned long long)f2bf(v.w) << 48);
  ((unsigned long long*)dst)[i] = p;
}

__device__ __forceinline__ void gload_lds16(const unsigned short* g, unsigned short* l) {
  __builtin_amdgcn_global_load_lds((const __attribute__((address_space(1))) unsigned int*)g,
                                   (__attribute__((address_space(3))) unsigned int*)l,
                                   16, 0, 0);
}

// logit[n, y_n] in exact f32: one wave per token row.
__global__ __launch_bounds__(256)
void tgt_dot(const float* __restrict__ x, const float* __restrict__ W,
             const int* __restrict__ y, float* __restrict__ tgtRow) {
  const int n = blockIdx.x * 4 + (threadIdx.x >> 6);
  const int lane = threadIdx.x & 63;
  const float4* xr = (const float4*)(x + (size_t)n * DIM);
  const float4* wr = (const float4*)(W + (size_t)y[n] * DIM);
  float d = 0.f;
#pragma unroll
  for (int i = 0; i < 4; ++i) {
    float4 a = xr[lane + 64 * i], b = wr[lane + 64 * i];
    d += a.x * b.x + a.y * b.y + a.z * b.z + a.w * b.w;
  }
#pragma unroll
  for (int off = 32; off > 0; off >>= 1) d += __shfl_xor(d, off, 64);
  if (lane == 0) tgtRow[n] = d;
}

// C = Xb[4096,1024] * Wb[32000,1024]^T with fused per-row sum(exp) / sum.
// 128x128 tile, 4 waves 2x2, BK=64 (2 MFMA k-steps per stage).
// grid.x = token tile (fastest) => XCD = linear%8 = ib%8: W reuse per XCD.
__global__ __launch_bounds__(256, 3)
void gemm_ce(const unsigned short* __restrict__ Xb, const unsigned short* __restrict__ Wb,
             float* __restrict__ rowExp, float* __restrict__ rowSum) {
  __shared__ __align__(16) unsigned short As[BM * BK];  // 16 KB, [128][64]
  __shared__ __align__(16) unsigned short Bs[BN * BK];  // 16 KB

  const int ib = blockIdx.x;   // token tile (32)
  const int jb = blockIdx.y;   // vocab tile (250)
  const int row0 = ib * BM;
  const int col0 = jb * BN;
  (void)col0;

  const int tid  = threadIdx.x;
  const int wv   = tid >> 6;
  const int lane = tid & 63;
  const int wr = wv >> 1, wc = wv & 1;
  const int quad = lane >> 4;
  const int r16  = lane & 15;
  // staging map: 1 KB per inst = 8 rows of 128 B; lane -> (row lane>>3, elem (lane&7)*8)
  const int lrow = lane >> 3;
  const int lcol = (lane & 7) * 8;

  float4v acc[4][4];
#pragma unroll
  for (int i = 0; i < 4; ++i)
#pragma unroll
    for (int j = 0; j < 4; ++j) acc[i][j] = (float4v){0.f, 0.f, 0.f, 0.f};

  for (int kk = 0; kk < DIM; kk += BK) {
    __syncthreads();   // prior ds_reads done before overwrite
#pragma unroll
    for (int c = 0; c < 4; ++c) {
      const int rA = wv * 32 + c * 8;   // wave-uniform 8-row slab base
      gload_lds16(Xb + (size_t)(row0 + rA + lrow) * DIM + kk + lcol, &As[rA * BK]);
      gload_lds16(Wb + (size_t)(col0 + rA + lrow) * DIM + kk + lcol, &Bs[rA * BK]);
    }
    __syncthreads();   // staging visible (vmcnt drain)

#pragma unroll
    for (int ks = 0; ks < 2; ++ks) {
      short8v af[4], bf[4];
#pragma unroll
      for (int i = 0; i < 4; ++i)
        af[i] = *(const short8v*)&As[(wr * 64 + i * 16 + r16) * BK + ks * 32 + quad * 8];
#pragma unroll
      for (int j = 0; j < 4; ++j)
        bf[j] = *(const short8v*)&Bs[(wc * 64 + j * 16 + r16) * BK + ks * 32 + quad * 8];
#pragma unroll
      for (int i = 0; i < 4; ++i)
#pragma unroll
        for (int j = 0; j < 4; ++j)
          acc[i][j] = __builtin_amdgcn_mfma_f32_16x16x32_bf16(af[i], bf[j], acc[i][j], 0, 0, 0);
    }
  }

  // Fused epilogue: per-row sum(exp(logit)), sum(logit).
  // C/D layout: col = r16, row = quad*4 + reg (within each 16x16 tile)
#pragma unroll
  for (int i = 0; i < 4; ++i)
#pragma unroll
    for (int r = 0; r < 4; ++r) {
      float se = 0.f, ss = 0.f;
#pragma unroll
      for (int j = 0; j < 4; ++j) {
        const float v = acc[i][j][r];
        ss += v;
        se += __expf(v);
      }
#pragma unroll
      for (int off = 1; off < 16; off <<= 1) {
        se += __shfl_xor(se, off, 64);
        ss += __shfl_xor(ss, off, 64);
      }
      if (r16 == 0) {
        const int rloc = wr * 64 + i * 16 + quad * 4 + r;
        atomicAdd(&rowExp[row0 + rloc], se);
        atomicAdd(&rowSum[row0 + rloc], ss);
      }
    }
}

// loss = (1/N) sum lse - (1-s)/N * sum tgt - s/(N*V) * sum(all logits)
__global__ void finalize_kernel(const float* __restrict__ rowExp, const float* __restrict__ rowSum,
                                const float* __restrict__ tgtRow, float* __restrict__ out) {
  __shared__ float s1[256], s2[256], s3[256];
  const int t = threadIdx.x;
  float a = 0.f, b = 0.f, c = 0.f;
  for (int n = t; n < N_TOK; n += 256) {
    a += logf(rowExp[n]);
    b += rowSum[n];
    c += tgtRow[n];
  }
  s1[t] = a; s2[t] = b; s3[t] = c;
  __syncthreads();
  for (int o = 128; o > 0; o >>= 1) {
    if (t < o) { s1[t] += s1[t + o]; s2[t] += s2[t + o]; s3[t] += s3[t + o]; }
    __syncthreads();
  }
  if (t == 0) {
    const float inviN = 1.0f / (float)N_TOK;
    out[0] = s1[0] * inviN
           - (1.0f - SMOOTH) * s3[0] * inviN
           - SMOOTH * s2[0] / ((float)N_TOK * (float)VOCAB);
  }
}

extern "C" void kernel_launch(void* const* d_in, const int* in_sizes, int n_in,
                              void* d_out, int out_size, void* d_ws, size_t ws_size,
                              hipStream_t stream) {
  const float* x = (const float*)d_in[0];
  const float* W = (const float*)d_in[1];
  const int*   y = (const int*)d_in[2];
  float* out = (float*)d_out;

  char* ws = (char*)d_ws;
  float* rowExp = (float*)(ws);              // 4096 f32
  float* rowSum = (float*)(ws + 16384);      // 4096 f32
  float* tgtRow = (float*)(ws + 32768);      // 4096 f32 (fully written, no memset)
  unsigned short* Xb = (unsigned short*)(ws + 65536);                            // 8.4 MB
  unsigned short* Wb = (unsigned short*)(ws + 65536 + (size_t)N_TOK * DIM * 2);  // 65.5 MB

  hipMemsetAsync(ws, 0, 32768, stream);  // zero rowExp/rowSum (ws poisoned 0xAA)

  tgt_dot<<<N_TOK / 4, 256, 0, stream>>>(x, W, y, tgtRow);
  cvt_bf16<<<(N_TOK * DIM / 4 + 255) / 256, 256, 0, stream>>>(x, Xb, N_TOK * DIM / 4);
  cvt_bf16<<<(VOCAB * DIM / 4 + 255) / 256, 256, 0, stream>>>(W, Wb, VOCAB * DIM / 4);

  dim3 grid(N_TOK / BM, VOCAB / BN);  // (32, 250): token-fastest for XCD locality
  gemm_ce<<<grid, 256, 0, stream>>>(Xb, Wb, rowExp, rowSum);

  finalize_kernel<<<1, 256, 0, stream>>>(rowExp, rowSum, tgtRow, out);
}

// Round 4
// 508.422 us; speedup vs baseline: 1.8417x; 1.1369x over previous
//
#include <hip/hip_runtime.h>
#include <hip/hip_bf16.h>

#define N_TOK 4096
#define DIM   1024
#define VOCAB 32000
#define BM 128
#define BN 128
#define BK 64           // 64-deep K stage: 32 MFMAs per barrier drain, 16 iters
#define SMOOTH 0.1f

typedef __attribute__((ext_vector_type(8))) short short8v;
typedef __attribute__((ext_vector_type(4))) float float4v;

__device__ __forceinline__ unsigned short f2bf(float f) {
  union { float f; unsigned u; } c; c.f = f;
  unsigned r = c.u + 0x7fffu + ((c.u >> 16) & 1u);
  return (unsigned short)(r >> 16);
}

// f32 -> bf16 (RNE) for BOTH tensors in one dispatch (trim launch gap).
__global__ void cvt_bf16_2(const float* __restrict__ a, unsigned short* __restrict__ da, int n4a,
                           const float* __restrict__ b, unsigned short* __restrict__ db, int n4b) {
  int i = blockIdx.x * blockDim.x + threadIdx.x;
  const float4* s; unsigned long long* d; int j;
  if (i < n4a)            { s = (const float4*)a; d = (unsigned long long*)da; j = i; }
  else if (i < n4a + n4b) { s = (const float4*)b; d = (unsigned long long*)db; j = i - n4a; }
  else return;
  float4 v = s[j];
  d[j] = (unsigned long long)f2bf(v.x)
       | ((unsigned long long)f2bf(v.y) << 16)
       | ((unsigned long long)f2bf(v.z) << 32)
       | ((unsigned long long)f2bf(v.w) << 48);
}

__device__ __forceinline__ void gload_lds16(const unsigned short* g, unsigned short* l) {
  __builtin_amdgcn_global_load_lds((const __attribute__((address_space(1))) unsigned int*)g,
                                   (__attribute__((address_space(3))) unsigned int*)l,
                                   16, 0, 0);
}

// logit[n, y_n] in exact f32: one wave per token row.
__global__ __launch_bounds__(256)
void tgt_dot(const float* __restrict__ x, const float* __restrict__ W,
             const int* __restrict__ y, float* __restrict__ tgtRow) {
  const int n = blockIdx.x * 4 + (threadIdx.x >> 6);
  const int lane = threadIdx.x & 63;
  const float4* xr = (const float4*)(x + (size_t)n * DIM);
  const float4* wr = (const float4*)(W + (size_t)y[n] * DIM);
  float d = 0.f;
#pragma unroll
  for (int i = 0; i < 4; ++i) {
    float4 a = xr[lane + 64 * i], b = wr[lane + 64 * i];
    d += a.x * b.x + a.y * b.y + a.z * b.z + a.w * b.w;
  }
#pragma unroll
  for (int off = 32; off > 0; off >>= 1) d += __shfl_xor(d, off, 64);
  if (lane == 0) tgtRow[n] = d;
}

// C = Xb[4096,1024] * Wb[32000,1024]^T with fused per-row sum(exp) / sum.
// 128x128 tile, 4 waves 2x2, BK=64. XOR-swizzled LDS: LDS[row][cb] holds
// global colblock cb ^ (row&7)  (cb = 8-bf16 = 16B block) -> ds_read_b128
// spreads all 8 colblocks across the 32 banks (was: 128B row stride = all
// rows on one 4-bank set = 38% of cycles in conflicts).
__global__ __launch_bounds__(256, 3)
void gemm_ce(const unsigned short* __restrict__ Xb, const unsigned short* __restrict__ Wb,
             float* __restrict__ rowExp, float* __restrict__ rowSum) {
  __shared__ __align__(16) unsigned short As[BM * BK];  // 16 KB, [128][64]
  __shared__ __align__(16) unsigned short Bs[BN * BK];  // 16 KB

  const int ib = blockIdx.x;   // token tile (32)
  const int jb = blockIdx.y;   // vocab tile (250)
  const int row0 = ib * BM;
  const int col0 = jb * BN;

  const int tid  = threadIdx.x;
  const int wv   = tid >> 6;
  const int lane = tid & 63;
  const int wr = wv >> 1, wc = wv & 1;
  const int quad = lane >> 4;
  const int r16  = lane & 15;
  // staging map: 1 KB per inst = 8 rows x 8 colblocks; LDS slot fixed at
  // base+lane*16, but lane FETCHES global colblock (lane&7)^(lrow&7).
  const int lrow = lane >> 3;
  const int gcb  = (lane & 7) ^ (lrow & 7);   // swizzled source colblock
  const int r8   = r16 & 7;                   // reader's row&7

  float4v acc[4][4];
#pragma unroll
  for (int i = 0; i < 4; ++i)
#pragma unroll
    for (int j = 0; j < 4; ++j) acc[i][j] = (float4v){0.f, 0.f, 0.f, 0.f};

  for (int kk = 0; kk < DIM; kk += BK) {
    __syncthreads();   // prior ds_reads done before overwrite
#pragma unroll
    for (int c = 0; c < 4; ++c) {
      const int rA = wv * 32 + c * 8;   // wave-uniform 8-row slab base
      gload_lds16(Xb + (size_t)(row0 + rA + lrow) * DIM + kk + gcb * 8, &As[rA * BK]);
      gload_lds16(Wb + (size_t)(col0 + rA + lrow) * DIM + kk + gcb * 8, &Bs[rA * BK]);
    }
    __syncthreads();   // staging visible (vmcnt drain)

#pragma unroll
    for (int ks = 0; ks < 2; ++ks) {
      const int cbA = (ks * 4 + quad) ^ r8;   // swizzled LDS colblock
      short8v af[4], bf[4];
#pragma unroll
      for (int i = 0; i < 4; ++i)
        af[i] = *(const short8v*)&As[(wr * 64 + i * 16 + r16) * BK + cbA * 8];
#pragma unroll
      for (int j = 0; j < 4; ++j)
        bf[j] = *(const short8v*)&Bs[(wc * 64 + j * 16 + r16) * BK + cbA * 8];
#pragma unroll
      for (int i = 0; i < 4; ++i)
#pragma unroll
        for (int j = 0; j < 4; ++j)
          acc[i][j] = __builtin_amdgcn_mfma_f32_16x16x32_bf16(af[i], bf[j], acc[i][j], 0, 0, 0);
    }
  }

  // Fused epilogue: per-row sum(exp(logit)), sum(logit).
  // C/D layout: col = r16, row = quad*4 + reg (within each 16x16 tile)
#pragma unroll
  for (int i = 0; i < 4; ++i)
#pragma unroll
    for (int r = 0; r < 4; ++r) {
      float se = 0.f, ss = 0.f;
#pragma unroll
      for (int j = 0; j < 4; ++j) {
        const float v = acc[i][j][r];
        ss += v;
        se += __expf(v);
      }
#pragma unroll
      for (int off = 1; off < 16; off <<= 1) {
        se += __shfl_xor(se, off, 64);
        ss += __shfl_xor(ss, off, 64);
      }
      if (r16 == 0) {
        const int rloc = wr * 64 + i * 16 + quad * 4 + r;
        atomicAdd(&rowExp[row0 + rloc], se);
        atomicAdd(&rowSum[row0 + rloc], ss);
      }
    }
}

// loss = (1/N) sum lse - (1-s)/N * sum tgt - s/(N*V) * sum(all logits)
__global__ void finalize_kernel(const float* __restrict__ rowExp, const float* __restrict__ rowSum,
                                const float* __restrict__ tgtRow, float* __restrict__ out) {
  __shared__ float s1[256], s2[256], s3[256];
  const int t = threadIdx.x;
  float a = 0.f, b = 0.f, c = 0.f;
  for (int n = t; n < N_TOK; n += 256) {
    a += logf(rowExp[n]);
    b += rowSum[n];
    c += tgtRow[n];
  }
  s1[t] = a; s2[t] = b; s3[t] = c;
  __syncthreads();
  for (int o = 128; o > 0; o >>= 1) {
    if (t < o) { s1[t] += s1[t + o]; s2[t] += s2[t + o]; s3[t] += s3[t + o]; }
    __syncthreads();
  }
  if (t == 0) {
    const float inviN = 1.0f / (float)N_TOK;
    out[0] = s1[0] * inviN
           - (1.0f - SMOOTH) * s3[0] * inviN
           - SMOOTH * s2[0] / ((float)N_TOK * (float)VOCAB);
  }
}

extern "C" void kernel_launch(void* const* d_in, const int* in_sizes, int n_in,
                              void* d_out, int out_size, void* d_ws, size_t ws_size,
                              hipStream_t stream) {
  const float* x = (const float*)d_in[0];
  const float* W = (const float*)d_in[1];
  const int*   y = (const int*)d_in[2];
  float* out = (float*)d_out;

  char* ws = (char*)d_ws;
  float* rowExp = (float*)(ws);              // 4096 f32
  float* rowSum = (float*)(ws + 16384);      // 4096 f32
  float* tgtRow = (float*)(ws + 32768);      // 4096 f32 (fully written, no memset)
  unsigned short* Xb = (unsigned short*)(ws + 65536);                            // 8.4 MB
  unsigned short* Wb = (unsigned short*)(ws + 65536 + (size_t)N_TOK * DIM * 2);  // 65.5 MB

  hipMemsetAsync(ws, 0, 32768, stream);  // zero rowExp/rowSum (ws poisoned 0xAA)

  tgt_dot<<<N_TOK / 4, 256, 0, stream>>>(x, W, y, tgtRow);

  const int n4x = N_TOK * DIM / 4, n4w = VOCAB * DIM / 4;
  cvt_bf16_2<<<(n4x + n4w + 255) / 256, 256, 0, stream>>>(x, Xb, n4x, W, Wb, n4w);

  dim3 grid(N_TOK / BM, VOCAB / BN);  // (32, 250): token-fastest for XCD locality
  gemm_ce<<<grid, 256, 0, stream>>>(Xb, Wb, rowExp, rowSum);

  finalize_kernel<<<1, 256, 0, stream>>>(rowExp, rowSum, tgtRow, out);
}